// Round 10
// baseline (231.130 us; speedup 1.0000x reference)
//
#include <hip/hip_runtime.h>
#include <hip/hip_bf16.h>
#include <stdint.h>

typedef uint16_t u16;
typedef uint32_t u32;
typedef __attribute__((ext_vector_type(8))) short bv8;    // 8 x bf16 (i16 bits), 4 VGPR
typedef __attribute__((ext_vector_type(4))) float f32x4;
typedef __attribute__((ext_vector_type(16))) float f32x16;
typedef __attribute__((ext_vector_type(2))) u32 u32x2;

#define MFMA(a,b,c)   __builtin_amdgcn_mfma_f32_16x16x32_bf16((a),(b),(c),0,0,0)
#define MFMA32(a,b,c) __builtin_amdgcn_mfma_f32_32x32x16_bf16((a),(b),(c),0,0,0)

__device__ __forceinline__ float bf2f(u16 v){ u32 x=(u32)v<<16; float f; __builtin_memcpy(&f,&x,4); return f; }
__device__ __forceinline__ u16 f2bf(float f){ u32 x; __builtin_memcpy(&x,&f,4); x += 0x7fffu + ((x>>16)&1u); return (u16)(x>>16); }
__device__ __forceinline__ u32 cvtpk_bf16(float lo, float hi){
  u32 r; asm("v_cvt_pk_bf16_f32 %0, %1, %2" : "=v"(r) : "v"(lo), "v"(hi)); return r;
}
__device__ __forceinline__ float exp2_fast(float x){
  float r; asm("v_exp_f32 %0, %1" : "=v"(r) : "v"(x)); return r;
}

__device__ __forceinline__ void gl_lds16(const u16* g, u16* l){
  __builtin_amdgcn_global_load_lds((const __attribute__((address_space(1))) u32*)g,
                                   (__attribute__((address_space(3))) u32*)l, 16, 0, 0);
}

// fp32 -> bf16 convert. n8 = elements/8.
__global__ __launch_bounds__(256) void cvt_bf16(const float* __restrict__ src, u16* __restrict__ dst, long n8){
  long i = (long)blockIdx.x*256 + threadIdx.x;
  long stride = (long)gridDim.x*256;
  for(; i<n8; i+=stride){
    f32x4 a = *(const f32x4*)(src + i*8);
    f32x4 b = *(const f32x4*)(src + i*8 + 4);
    bv8 o;
    #pragma unroll
    for(int j=0;j<4;j++) o[j]   = (short)f2bf(a[j]);
    #pragma unroll
    for(int j=0;j<4;j++) o[4+j] = (short)f2bf(b[j]);
    *(bv8*)(dst + i*8) = o;
  }
}

// ---------------------------------------------------------------------------
// C[m,n] = sum_k A[m,k] * B[n,k]   (A: MxK bf16 row-major, B: NxK bf16)
// 128x128 tile, BK=64, 4 waves, global_load_lds w/ pre-swizzled src.
// ---------------------------------------------------------------------------
template<bool OUTF32>
__global__ __launch_bounds__(256,2) void gemm_bt(const u16* __restrict__ A, const u16* __restrict__ B,
                                                 void* __restrict__ Cv, int M, int N, int K){
  __shared__ __align__(16) u16 As[128*64];
  __shared__ __align__(16) u16 Bs[128*64];
  int nwg = gridDim.x;
  int wg  = (int)blockIdx.x;
  wg = (wg & 7)*(nwg>>3) + (wg>>3);          // XCD swizzle (nwg % 8 == 0)
  int nn = N>>7;
  int tm = wg/nn, tn = wg - tm*nn;
  int rowbase = tm<<7, colbase = tn<<7;
  int t = threadIdx.x, lane = t&63, w = t>>6;
  int g = lane>>4, q16 = lane&15;
  int wr = w>>1, wc = w&1;

  f32x4 z = {0.f,0.f,0.f,0.f};
  f32x4 acc[4][4];
  #pragma unroll
  for(int i=0;i<4;i++)
    #pragma unroll
    for(int j=0;j<4;j++) acc[i][j]=z;

  for(int k0=0;k0<K;k0+=64){
    __syncthreads();
    #pragma unroll
    for(int i=0;i<4;i++){
      int s = ((w<<2)+i)*64 + lane;
      int row = s>>3;
      int ksl = (s&7) ^ (row&7);
      gl_lds16(A + (size_t)(rowbase+row)*K + k0 + ksl*8, (u16*)As + ((w<<2)+i)*512);
      gl_lds16(B + (size_t)(colbase+row)*K + k0 + ksl*8, (u16*)Bs + ((w<<2)+i)*512);
    }
    __syncthreads();
    #pragma unroll
    for(int eks=0;eks<2;eks++){
      bv8 af[4], bfr[4];
      #pragma unroll
      for(int mi=0;mi<4;mi++){
        int row = (wr<<6)+(mi<<4)+q16;
        af[mi] = *(const bv8*)(As + row*64 + ((((eks<<2)|g) ^ (row&7))<<3));
      }
      #pragma unroll
      for(int ni=0;ni<4;ni++){
        int row = (wc<<6)+(ni<<4)+q16;
        bfr[ni] = *(const bv8*)(Bs + row*64 + ((((eks<<2)|g) ^ (row&7))<<3));
      }
      #pragma unroll
      for(int mi=0;mi<4;mi++)
        #pragma unroll
        for(int ni=0;ni<4;ni++)
          acc[mi][ni] = MFMA(af[mi], bfr[ni], acc[mi][ni]);
    }
  }
  #pragma unroll
  for(int mi=0;mi<4;mi++){
    #pragma unroll
    for(int ni=0;ni<4;ni++){
      int row = rowbase + (wr<<6) + (mi<<4) + (g<<2);
      int col = colbase + (wc<<6) + (ni<<4) + q16;
      if(OUTF32){
        float* cp = (float*)Cv + (size_t)row*N + col;
        #pragma unroll
        for(int r=0;r<4;r++) cp[(size_t)r*N] = acc[mi][ni][r];
      } else {
        u16* cp = (u16*)Cv + (size_t)row*N + col;
        #pragma unroll
        for(int r=0;r<4;r++) cp[(size_t)r*N] = f2bf(acc[mi][ni][r]);
      }
    }
  }
}

// ---------------------------------------------------------------------------
// In-place RMSNorm + RoPE on q,k of qkv. One wave per row of 64.
// q rows scaled by (1/8)*log2(e): softmax scale + exp2-domain fold.
// ---------------------------------------------------------------------------
__global__ __launch_bounds__(256) void normrope(u16* __restrict__ qkv, const float* __restrict__ cosT,
                                                const float* __restrict__ sinT, const float* __restrict__ qw,
                                                const float* __restrict__ kw){
  int t = threadIdx.x, lane = t&63, wv = t>>6;
  long gid = (long)blockIdx.x*4 + wv;        // over B*L*2*H = 262144 rows
  int h = (int)(gid & 15);
  int s = (int)((gid>>4) & 1);
  long bl = gid >> 5;                        // 0..8191
  int l = (int)(bl & 1023);
  u16* p = qkv + bl*3072 + s*1024 + h*64 + lane;
  float x = bf2f(*p);
  float ss = x*x;
  #pragma unroll
  for(int m=1;m<64;m<<=1) ss += __shfl_xor(ss, m, 64);
  float nrm = rsqrtf(ss*(1.f/64.f) + 1e-6f);
  float y = x * nrm * (s ? kw[lane] : qw[lane]);
  float other = __shfl_xor(y, 32, 64);
  float rot = (lane<32)? -other : other;     // rotate_half
  int ci = l*64 + lane;
  float outv = y*cosT[ci] + rot*sinT[ci];
  *p = f2bf(s ? outv : outv*0.1803368801111437f);   // 0.125 * log2(e)
}

// ---------------------------------------------------------------------------
// Flash attention, 32x32x16 MFMA. 4 waves x 32 q-rows (BQ=128), KV tile 128.
// Full-tile QK^T (4 accumulators s0..s3 = kv rows 0-31/32-63/64-95/96-127),
// then ONE softmax pass (explicit tree max/sum), then 8 PV steps.
// K double-buffered via global_load_lds DMA; V^T in LDS (validated layouts).
// Defer-max (T13). P->PV A-frag: dual-payload shfl_xor(32) exchange.
// ---------------------------------------------------------------------------
__global__ __launch_bounds__(256,3) void fattn(const u16* __restrict__ qkv, u16* __restrict__ Out){
  __shared__ __align__(16) u16 Ks0[128*64];     // 16KB [kv][e], slot^=(kv&7)
  __shared__ __align__(16) u16 Ks1[128*64];     // 16KB
  __shared__ __align__(16) u16 Vt[64*128];      // 16KB [d][kv], slot^=(d&15)

  int t = threadIdx.x, lane = t&63, w = t>>6;
  int ql = lane&31, h = lane>>5;
  int nwg = gridDim.x;
  int bid = (int)blockIdx.x;
  bid = (bid & 7)*(nwg>>3) + (bid>>3);          // XCD swizzle (nwg=1024)
  int bh = bid >> 3, qt = bid & 7;              // 8 q-tiles of 128 rows
  int b = bh >> 4, hd = bh & 15;
  const u16* base = qkv + (size_t)b*1024*3072;
  int Qb = (qt<<7) + (w<<5);                    // wave's 32 q-rows

  // Q B-frags: qf[s] holds Q[Qb+ql][d=16s+8h+0..7]
  bv8 qf[4];
  {
    const u16* qp = base + (size_t)(Qb+ql)*3072 + hd*64 + (h<<3);
    qf[0] = *(const bv8*)(qp);
    qf[1] = *(const bv8*)(qp+16);
    qf[2] = *(const bv8*)(qp+32);
    qf[3] = *(const bv8*)(qp+48);
  }
  f32x16 accO0, accO1;
  #pragma unroll
  for(int r=0;r<16;r++){ accO0[r]=0.f; accO1[r]=0.f; }
  float m_run = -1e30f, l_run = 0.f;

  // V staging geometry (validated R8/R9)
  int d0v = (t&7)<<3;
  int c4  = t>>3;
  int sV = c4>>1, halfV = c4&1, kvr = c4<<2;
  int d15b = (t&1)<<3;
  int dsw = ql & 15;

  bv8 v0,v1,v2,v3;
  const u16* gV0 = base + (size_t)kvr*3072 + 2048 + hd*64 + d0v;

#define LDV(tl) { const u16* gV = gV0 + (size_t)(tl)*393216; \
    v0 = *(const bv8*)(gV);       v1 = *(const bv8*)(gV+3072); \
    v2 = *(const bv8*)(gV+6144);  v3 = *(const bv8*)(gV+9216); }

#define STV() { \
    _Pragma("unroll") \
    for(int i=0;i<8;i++){ \
      int d = d0v + i; \
      u32x2 val; \
      val.x = (u32)(u16)v0[i] | ((u32)(u16)v1[i]<<16); \
      val.y = (u32)(u16)v2[i] | ((u32)(u16)v3[i]<<16); \
      *(u32x2*)(Vt + d*128 + (((sV ^ (d15b+i))<<3) + (halfV<<2))) = val; \
    } }

#define KDMA(tl, buf) { \
    _Pragma("unroll") \
    for(int i=0;i<4;i++){ \
      int si = ((w<<2)+i)*64 + lane; \
      int row = si>>3; \
      int esl = (si&7) ^ (row&7); \
      gl_lds16(base + (size_t)(((tl)<<7)+row)*3072 + 1024 + hd*64 + esl*8, (buf) + ((w<<2)+i)*512); \
    } }

// one PV step: A-frag from SV regs [4*b0 .. 4*b0+7], V slot base sb (=2*tt+8*sub)
#define PVQ(SV, b0, sb) { \
    u32 Wlo0 = cvtpk_bf16(SV[4*(b0)+0], SV[4*(b0)+1]); \
    u32 Wlo1 = cvtpk_bf16(SV[4*(b0)+2], SV[4*(b0)+3]); \
    u32 Whi0 = cvtpk_bf16(SV[4*(b0)+4], SV[4*(b0)+5]); \
    u32 Whi1 = cvtpk_bf16(SV[4*(b0)+6], SV[4*(b0)+7]); \
    u32 X0 = h ? Wlo0 : Whi0; \
    u32 X1 = h ? Wlo1 : Whi1; \
    u32 x0 = (u32)__shfl_xor((int)X0, 32, 64); \
    u32 x1 = (u32)__shfl_xor((int)X1, 32, 64); \
    union { u32 u[4]; bv8 v; } pf; \
    pf.u[0] = h ? x0 : Wlo0; \
    pf.u[1] = h ? x1 : Wlo1; \
    pf.u[2] = h ? Whi0 : x0; \
    pf.u[3] = h ? Whi1 : x1; \
    int vslot = ((sb) + h) ^ dsw; \
    bv8 vf0 = *(const bv8*)(Vt + ql*128 + (vslot<<3)); \
    bv8 vf1 = *(const bv8*)(Vt + (32+ql)*128 + (vslot<<3)); \
    __builtin_amdgcn_s_setprio(1); \
    accO0 = MFMA32(pf.v, vf0, accO0); \
    accO1 = MFMA32(pf.v, vf1, accO1); \
    __builtin_amdgcn_s_setprio(0); }

  // prologue: K(0) DMA, V(0) regs
  KDMA(0, (u16*)Ks0);
  LDV(0);

  for(int tile=0; tile<8; ++tile){
    u16* kcur = (tile&1) ? (u16*)Ks1 : (u16*)Ks0;
    u16* knxt = (tile&1) ? (u16*)Ks0 : (u16*)Ks1;
    if(tile>0) __syncthreads();     // all waves done reading Vt & knxt
    STV();                          // write V(tile)
    __syncthreads();                // Vt visible; K(tile) DMA drained
    if(tile<7){
      KDMA(tile+1, knxt);           // DMA overlaps this tile's compute
      LDV(tile+1);                  // regs for next STV
    }

    // ---- QK^T over all 128 kv: s0..s3 = S^T rows {0-31,32-63,64-95,96-127}
    f32x16 s0, s1, s2, s3;
    #pragma unroll
    for(int r=0;r<16;r++){ s0[r]=0.f; s1[r]=0.f; s2[r]=0.f; s3[r]=0.f; }
    int esw = ql & 7;                     // row&7 identical for ql, 32+ql, 64+ql, 96+ql
    __builtin_amdgcn_s_setprio(1);
    #pragma unroll
    for(int sI=0;sI<4;sI++){
      int sl = (((sI<<1)|h) ^ esw) << 3;
      bv8 k0 = *(const bv8*)(kcur + ql*64        + sl);
      bv8 k1 = *(const bv8*)(kcur + (32+ql)*64   + sl);
      bv8 k2 = *(const bv8*)(kcur + (64+ql)*64   + sl);
      bv8 k3 = *(const bv8*)(kcur + (96+ql)*64   + sl);
      s0 = MFMA32(k0, qf[sI], s0);
      s1 = MFMA32(k1, qf[sI], s1);
      s2 = MFMA32(k2, qf[sI], s2);
      s3 = MFMA32(k3, qf[sI], s3);
    }
    __builtin_amdgcn_s_setprio(0);

    // ---- single softmax pass (lane owns q-col ql; partner at lane^32)
    float tm16[16];
    #pragma unroll
    for(int r=0;r<16;r++) tm16[r] = fmaxf(fmaxf(s0[r],s1[r]), fmaxf(s2[r],s3[r]));
    #pragma unroll
    for(int d=8; d>=1; d>>=1)
      #pragma unroll
      for(int r=0;r<8;r++) if(r<d) tm16[r] = fmaxf(tm16[r], tm16[r+d]);
    float rm = tm16[0];
    rm = fmaxf(rm, __shfl_xor(rm, 32, 64));
    if(__any(rm > m_run + 8.0f)){         // defer-max (T13)
      float mnew = fmaxf(m_run, rm);
      float fac = exp2_fast(m_run - mnew);
      m_run = mnew;
      l_run *= fac;
      #pragma unroll
      for(int r=0;r<16;r++){
        int qs = (r&3) + ((r>>2)<<3) + (h<<2);
        float fr = __shfl(fac, qs, 64);
        accO0[r] *= fr; accO1[r] *= fr;
      }
    }
    #pragma unroll
    for(int r=0;r<16;r++){
      s0[r] = exp2_fast(s0[r]-m_run);
      s1[r] = exp2_fast(s1[r]-m_run);
      s2[r] = exp2_fast(s2[r]-m_run);
      s3[r] = exp2_fast(s3[r]-m_run);
    }
    float ts16[16];
    #pragma unroll
    for(int r=0;r<16;r++) ts16[r] = (s0[r]+s1[r]) + (s2[r]+s3[r]);
    #pragma unroll
    for(int d=8; d>=1; d>>=1)
      #pragma unroll
      for(int r=0;r<8;r++) if(r<d) ts16[r] += ts16[r+d];
    float ps = ts16[0];
    ps += __shfl_xor(ps, 32, 64);
    l_run += ps;

    // ---- PV: O[32q][64d] += P[32q][128kv] * V[128kv][64d]
    PVQ(s0, 0, 0)  PVQ(s0, 2, 2)
    PVQ(s1, 0, 4)  PVQ(s1, 2, 6)
    PVQ(s2, 0, 8)  PVQ(s2, 2, 10)
    PVQ(s3, 0, 12) PVQ(s3, 2, 14)
  }
  // ---- epilogue: divide by l (per-q broadcast) and store
  float linv = 1.f/l_run;
  #pragma unroll
  for(int r=0;r<16;r++){
    int qs = (r&3) + ((r>>2)<<3) + (h<<2);
    float li = __shfl(linv, qs, 64);
    size_t o = (size_t)(b*1024 + Qb + qs)*1024 + hd*64 + ql;
    Out[o]      = f2bf(accO0[r]*li);
    Out[o + 32] = f2bf(accO1[r]*li);
  }
#undef LDV
#undef STV
#undef KDMA
#undef PVQ
}

extern "C" void kernel_launch(void* const* d_in, const int* in_sizes, int n_in,
                              void* d_out, int out_size, void* d_ws, size_t ws_size,
                              hipStream_t stream) {
  const float* x      = (const float*)d_in[0];
  const float* cosT   = (const float*)d_in[1];
  const float* sinT   = (const float*)d_in[2];
  const float* w_qkv  = (const float*)d_in[3];
  const float* w_proj = (const float*)d_in[4];
  const float* qw     = (const float*)d_in[5];
  const float* kw     = (const float*)d_in[6];
  float* out = (float*)d_out;

  // ws layout (u16 units): xb dead after qkv GEMM -> attn aliases it.
  u16* xb     = (u16*)d_ws;                         //  8388608 elems
  u16* wqkvb  = xb     + (size_t) 8388608;          //  3145728
  u16* wprojb = wqkvb  + (size_t) 3145728;          //  1048576
  u16* qkv    = wprojb + (size_t) 1048576;          // 25165824
  u16* attn   = xb;                                 //  8388608 (alias)

  cvt_bf16<<<2048, 256, 0, stream>>>(x,      xb,     1048576);
  cvt_bf16<<<1536, 256, 0, stream>>>(w_qkv,  wqkvb,   393216);
  cvt_bf16<<< 512, 256, 0, stream>>>(w_proj, wprojb,  131072);

  gemm_bt<false><<<1536, 256, 0, stream>>>(xb, wqkvb, qkv, 8192, 3072, 1024);
  normrope<<<65536, 256, 0, stream>>>(qkv, cosT, sinT, qw, kw);
  fattn   <<<1024, 256, 0, stream>>>(qkv, attn);
  gemm_bt<true><<<512, 256, 0, stream>>>(attn, wprojb, out, 8192, 1024, 1024);
}

// Round 11
// 188.598 us; speedup vs baseline: 1.2255x; 1.2255x over previous
//
#include <hip/hip_runtime.h>
#include <hip/hip_bf16.h>
#include <stdint.h>

typedef uint16_t u16;
typedef uint32_t u32;
typedef __attribute__((ext_vector_type(8))) short bv8;    // 8 x bf16 (i16 bits), 4 VGPR
typedef __attribute__((ext_vector_type(4))) float f32x4;
typedef __attribute__((ext_vector_type(16))) float f32x16;
typedef __attribute__((ext_vector_type(2))) u32 u32x2;

#define MFMA(a,b,c)   __builtin_amdgcn_mfma_f32_16x16x32_bf16((a),(b),(c),0,0,0)
#define MFMA32(a,b,c) __builtin_amdgcn_mfma_f32_32x32x16_bf16((a),(b),(c),0,0,0)

__device__ __forceinline__ float bf2f(u16 v){ u32 x=(u32)v<<16; float f; __builtin_memcpy(&f,&x,4); return f; }
__device__ __forceinline__ u16 f2bf(float f){ u32 x; __builtin_memcpy(&x,&f,4); x += 0x7fffu + ((x>>16)&1u); return (u16)(x>>16); }
__device__ __forceinline__ u32 cvtpk_bf16(float lo, float hi){
  u32 r; asm("v_cvt_pk_bf16_f32 %0, %1, %2" : "=v"(r) : "v"(lo), "v"(hi)); return r;
}
__device__ __forceinline__ float exp2_fast(float x){
  float r; asm("v_exp_f32 %0, %1" : "=v"(r) : "v"(x)); return r;
}

__device__ __forceinline__ void gl_lds16(const u16* g, u16* l){
  __builtin_amdgcn_global_load_lds((const __attribute__((address_space(1))) u32*)g,
                                   (__attribute__((address_space(3))) u32*)l, 16, 0, 0);
}

// fp32 -> bf16 convert. n8 = elements/8.
__global__ __launch_bounds__(256) void cvt_bf16(const float* __restrict__ src, u16* __restrict__ dst, long n8){
  long i = (long)blockIdx.x*256 + threadIdx.x;
  long stride = (long)gridDim.x*256;
  for(; i<n8; i+=stride){
    f32x4 a = *(const f32x4*)(src + i*8);
    f32x4 b = *(const f32x4*)(src + i*8 + 4);
    bv8 o;
    #pragma unroll
    for(int j=0;j<4;j++) o[j]   = (short)f2bf(a[j]);
    #pragma unroll
    for(int j=0;j<4;j++) o[4+j] = (short)f2bf(b[j]);
    *(bv8*)(dst + i*8) = o;
  }
}

// ---------------------------------------------------------------------------
// C[m,n] = sum_k A[m,k] * B[n,k]   (A: MxK bf16 row-major, B: NxK bf16)
// 128x128 tile, BK=64, 4 waves, global_load_lds w/ pre-swizzled src.
// MODE 0: bf16 out. MODE 1: fp32 out. MODE 2: bf16 out + fused RMSNorm+RoPE
// on q/k column range (qkv GEMM; N=3072, cols<2048 are q/k, col-tile never
// straddles; wave subtile = one head of 64 dims).
// ---------------------------------------------------------------------------
template<int MODE>
__global__ __launch_bounds__(256,2) void gemm_bt(const u16* __restrict__ A, const u16* __restrict__ B,
                                                 void* __restrict__ Cv, int M, int N, int K,
                                                 const float* __restrict__ cosT,
                                                 const float* __restrict__ sinT,
                                                 const float* __restrict__ qw,
                                                 const float* __restrict__ kw){
  __shared__ __align__(16) u16 As[128*64];
  __shared__ __align__(16) u16 Bs[128*64];
  int nwg = gridDim.x;
  int wg  = (int)blockIdx.x;
  wg = (wg & 7)*(nwg>>3) + (wg>>3);          // XCD swizzle (nwg % 8 == 0)
  int nn = N>>7;
  int tm = wg/nn, tn = wg - tm*nn;
  int rowbase = tm<<7, colbase = tn<<7;
  int t = threadIdx.x, lane = t&63, w = t>>6;
  int g = lane>>4, q16 = lane&15;
  int wr = w>>1, wc = w&1;

  f32x4 z = {0.f,0.f,0.f,0.f};
  f32x4 acc[4][4];
  #pragma unroll
  for(int i=0;i<4;i++)
    #pragma unroll
    for(int j=0;j<4;j++) acc[i][j]=z;

  for(int k0=0;k0<K;k0+=64){
    __syncthreads();
    #pragma unroll
    for(int i=0;i<4;i++){
      int s = ((w<<2)+i)*64 + lane;
      int row = s>>3;
      int ksl = (s&7) ^ (row&7);
      gl_lds16(A + (size_t)(rowbase+row)*K + k0 + ksl*8, (u16*)As + ((w<<2)+i)*512);
      gl_lds16(B + (size_t)(colbase+row)*K + k0 + ksl*8, (u16*)Bs + ((w<<2)+i)*512);
    }
    __syncthreads();
    #pragma unroll
    for(int eks=0;eks<2;eks++){
      bv8 af[4], bfr[4];
      #pragma unroll
      for(int mi=0;mi<4;mi++){
        int row = (wr<<6)+(mi<<4)+q16;
        af[mi] = *(const bv8*)(As + row*64 + ((((eks<<2)|g) ^ (row&7))<<3));
      }
      #pragma unroll
      for(int ni=0;ni<4;ni++){
        int row = (wc<<6)+(ni<<4)+q16;
        bfr[ni] = *(const bv8*)(Bs + row*64 + ((((eks<<2)|g) ^ (row&7))<<3));
      }
      #pragma unroll
      for(int mi=0;mi<4;mi++)
        #pragma unroll
        for(int ni=0;ni<4;ni++)
          acc[mi][ni] = MFMA(af[mi], bfr[ni], acc[mi][ni]);
    }
  }

  if(MODE==2 && colbase < 2048){
    // fused RMSNorm + RoPE (+ q pre-scale 0.125*log2e) on this q/k head
    int s = colbase>>10;                       // 0=q, 1=k
    const float* wsel = s ? kw : qw;
    int ch = colbase + (wc<<6);
    float qsc = s ? 1.0f : 0.1803368801111437f;
    float wv[4];
    #pragma unroll
    for(int ni=0;ni<4;ni++) wv[ni] = wsel[(ni<<4)|q16];
    #pragma unroll
    for(int mi=0;mi<4;mi++){
      #pragma unroll
      for(int r=0;r<4;r++){
        int row = rowbase + (wr<<6)+(mi<<4)+(g<<2)+r;
        int l = row & 1023;
        float y[4];
        float ss = 0.f;
        #pragma unroll
        for(int ni=0;ni<4;ni++){ y[ni]=acc[mi][ni][r]; ss += y[ni]*y[ni]; }
        ss += __shfl_xor(ss,1,64); ss += __shfl_xor(ss,2,64);
        ss += __shfl_xor(ss,4,64); ss += __shfl_xor(ss,8,64);
        float nrm = rsqrtf(ss*(1.f/64.f) + 1e-6f);
        #pragma unroll
        for(int ni=0;ni<4;ni++) y[ni] *= nrm * wv[ni];
        u16* cp = (u16*)Cv + (size_t)row*N + ch;
        #pragma unroll
        for(int ni=0;ni<4;ni++){
          int d = (ni<<4)|q16;
          float rot = (ni<2) ? -y[ni+2] : y[ni-2];  // rotate_half pairing d^32
          float o = (y[ni]*cosT[l*64+d] + rot*sinT[l*64+d]) * qsc;
          cp[d] = f2bf(o);
        }
      }
    }
    return;
  }

  #pragma unroll
  for(int mi=0;mi<4;mi++){
    #pragma unroll
    for(int ni=0;ni<4;ni++){
      int row = rowbase + (wr<<6) + (mi<<4) + (g<<2);
      int col = colbase + (wc<<6) + (ni<<4) + q16;
      if(MODE==1){
        float* cp = (float*)Cv + (size_t)row*N + col;
        #pragma unroll
        for(int r=0;r<4;r++) cp[(size_t)r*N] = acc[mi][ni][r];
      } else {
        u16* cp = (u16*)Cv + (size_t)row*N + col;
        #pragma unroll
        for(int r=0;r<4;r++) cp[(size_t)r*N] = f2bf(acc[mi][ni][r]);
      }
    }
  }
}

// ---------------------------------------------------------------------------
// Flash attention, 32x32x16 MFMA (R9-validated, 80 us). 4 waves x 32 q-rows
// (BQ=128), KV tile 128 as 2 sub-rounds of 64 kv. Swapped QK^T; K dbuf DMA;
// V^T in LDS; defer-max; dual-payload shfl_xor(32) P exchange.
// ---------------------------------------------------------------------------
__global__ __launch_bounds__(256,3) void fattn(const u16* __restrict__ qkv, u16* __restrict__ Out){
  __shared__ __align__(16) u16 Ks0[128*64];     // 16KB [kv][e], slot^=(kv&7)
  __shared__ __align__(16) u16 Ks1[128*64];     // 16KB
  __shared__ __align__(16) u16 Vt[64*128];      // 16KB [d][kv], slot^=(d&15)

  int t = threadIdx.x, lane = t&63, w = t>>6;
  int ql = lane&31, h = lane>>5;
  int nwg = gridDim.x;
  int bid = (int)blockIdx.x;
  bid = (bid & 7)*(nwg>>3) + (bid>>3);          // XCD swizzle (nwg=1024)
  int bh = bid >> 3, qt = bid & 7;              // 8 q-tiles of 128 rows
  int b = bh >> 4, hd = bh & 15;
  const u16* base = qkv + (size_t)b*1024*3072;
  int Qb = (qt<<7) + (w<<5);                    // wave's 32 q-rows

  bv8 qf[4];
  {
    const u16* qp = base + (size_t)(Qb+ql)*3072 + hd*64 + (h<<3);
    qf[0] = *(const bv8*)(qp);
    qf[1] = *(const bv8*)(qp+16);
    qf[2] = *(const bv8*)(qp+32);
    qf[3] = *(const bv8*)(qp+48);
  }
  f32x16 accO0, accO1;
  #pragma unroll
  for(int r=0;r<16;r++){ accO0[r]=0.f; accO1[r]=0.f; }
  float m_run = -1e30f, l_run = 0.f;

  int d0v = (t&7)<<3;
  int c4  = t>>3;
  int sV = c4>>1, halfV = c4&1, kvr = c4<<2;
  int d15b = (t&1)<<3;

  bv8 v0,v1,v2,v3;
  const u16* gV0 = base + (size_t)kvr*3072 + 2048 + hd*64 + d0v;

#define LDV(tl) { const u16* gV = gV0 + (size_t)(tl)*393216; \
    v0 = *(const bv8*)(gV);       v1 = *(const bv8*)(gV+3072); \
    v2 = *(const bv8*)(gV+6144);  v3 = *(const bv8*)(gV+9216); }

#define STV() { \
    _Pragma("unroll") \
    for(int i=0;i<8;i++){ \
      int d = d0v + i; \
      u32x2 val; \
      val.x = (u32)(u16)v0[i] | ((u32)(u16)v1[i]<<16); \
      val.y = (u32)(u16)v2[i] | ((u32)(u16)v3[i]<<16); \
      *(u32x2*)(Vt + d*128 + (((sV ^ (d15b+i))<<3) + (halfV<<2))) = val; \
    } }

#define KDMA(tl, buf) { \
    _Pragma("unroll") \
    for(int i=0;i<4;i++){ \
      int si = ((w<<2)+i)*64 + lane; \
      int row = si>>3; \
      int esl = (si&7) ^ (row&7); \
      gl_lds16(base + (size_t)(((tl)<<7)+row)*3072 + 1024 + hd*64 + esl*8, (buf) + ((w<<2)+i)*512); \
    } }

  // prologue: K(0) DMA, V(0) regs
  KDMA(0, (u16*)Ks0);
  LDV(0);

  for(int tile=0; tile<8; ++tile){
    u16* kcur = (tile&1) ? (u16*)Ks1 : (u16*)Ks0;
    u16* knxt = (tile&1) ? (u16*)Ks0 : (u16*)Ks1;
    if(tile>0) __syncthreads();     // all waves done reading Vt & knxt
    STV();                          // write V(tile)
    __syncthreads();                // Vt visible; K(tile) DMA drained
    if(tile<7){
      KDMA(tile+1, knxt);           // DMA overlaps this tile's compute
      LDV(tile+1);                  // regs for next STV
    }

    #pragma unroll
    for(int sub=0; sub<2; ++sub){
      f32x16 s0, s1;
      #pragma unroll
      for(int r=0;r<16;r++){ s0[r]=0.f; s1[r]=0.f; }
      int rowA = (sub<<6) + ql;
      int rowB = rowA + 32;
      __builtin_amdgcn_s_setprio(1);
      #pragma unroll
      for(int s=0;s<4;s++){
        bv8 ka = *(const bv8*)(kcur + rowA*64 + ((((s<<1)|h) ^ (rowA&7))<<3));
        bv8 kb = *(const bv8*)(kcur + rowB*64 + ((((s<<1)|h) ^ (rowB&7))<<3));
        s0 = MFMA32(ka, qf[s], s0);
        s1 = MFMA32(kb, qf[s], s1);
      }
      __builtin_amdgcn_s_setprio(0);

      float rm = -1e30f;
      #pragma unroll
      for(int r=0;r<16;r++){ rm = fmaxf(rm, fmaxf(s0[r], s1[r])); }
      rm = fmaxf(rm, __shfl_xor(rm, 32, 64));
      if(__any(rm > m_run + 8.0f)){         // defer-max
        float mnew = fmaxf(m_run, rm);
        float fac = exp2_fast(m_run - mnew);
        m_run = mnew;
        l_run *= fac;
        #pragma unroll
        for(int r=0;r<16;r++){
          int qs = (r&3) + ((r>>2)<<3) + (h<<2);
          float fr = __shfl(fac, qs, 64);
          accO0[r] *= fr; accO1[r] *= fr;
        }
      }
      float ps = 0.f;
      #pragma unroll
      for(int r=0;r<16;r++){
        float p0 = exp2_fast(s0[r]-m_run); s0[r] = p0;
        float p1 = exp2_fast(s1[r]-m_run); s1[r] = p1;
        ps += p0 + p1;
      }
      ps += __shfl_xor(ps, 32, 64);
      l_run += ps;

      int dsw = ql & 15;
      #pragma unroll
      for(int tt=0; tt<4; ++tt){
        int b0 = (tt&1)<<1;
        float a0,a1,a2,a3,b4,b5,b6,b7;
        if(tt<2){ a0=s0[4*b0+0]; a1=s0[4*b0+1]; a2=s0[4*b0+2]; a3=s0[4*b0+3];
                  b4=s0[4*b0+4]; b5=s0[4*b0+5]; b6=s0[4*b0+6]; b7=s0[4*b0+7]; }
        else    { a0=s1[4*b0+0]; a1=s1[4*b0+1]; a2=s1[4*b0+2]; a3=s1[4*b0+3];
                  b4=s1[4*b0+4]; b5=s1[4*b0+5]; b6=s1[4*b0+6]; b7=s1[4*b0+7]; }
        u32 Wlo0 = cvtpk_bf16(a0,a1), Wlo1 = cvtpk_bf16(a2,a3);
        u32 Whi0 = cvtpk_bf16(b4,b5), Whi1 = cvtpk_bf16(b6,b7);
        u32 X0 = h ? Wlo0 : Whi0;
        u32 X1 = h ? Wlo1 : Whi1;
        u32 x0 = (u32)__shfl_xor((int)X0, 32, 64);
        u32 x1 = (u32)__shfl_xor((int)X1, 32, 64);
        union { u32 u[4]; bv8 v; } pf;
        pf.u[0] = h ? x0 : Wlo0;
        pf.u[1] = h ? x1 : Wlo1;
        pf.u[2] = h ? Whi0 : x0;
        pf.u[3] = h ? Whi1 : x1;
        int vslot = ((sub<<3)+(tt<<1)+h) ^ dsw;
        bv8 vf0 = *(const bv8*)(Vt + ql*128 + (vslot<<3));
        bv8 vf1 = *(const bv8*)(Vt + (32+ql)*128 + (vslot<<3));
        __builtin_amdgcn_s_setprio(1);
        accO0 = MFMA32(pf.v, vf0, accO0);
        accO1 = MFMA32(pf.v, vf1, accO1);
        __builtin_amdgcn_s_setprio(0);
      }
    }
  }
  float linv = 1.f/l_run;
  #pragma unroll
  for(int r=0;r<16;r++){
    int qs = (r&3) + ((r>>2)<<3) + (h<<2);
    float li = __shfl(linv, qs, 64);
    size_t o = (size_t)(b*1024 + Qb + qs)*1024 + hd*64 + ql;
    Out[o]      = f2bf(accO0[r]*li);
    Out[o + 32] = f2bf(accO1[r]*li);
  }
#undef LDV
#undef STV
#undef KDMA
}

extern "C" void kernel_launch(void* const* d_in, const int* in_sizes, int n_in,
                              void* d_out, int out_size, void* d_ws, size_t ws_size,
                              hipStream_t stream) {
  const float* x      = (const float*)d_in[0];
  const float* cosT   = (const float*)d_in[1];
  const float* sinT   = (const float*)d_in[2];
  const float* w_qkv  = (const float*)d_in[3];
  const float* w_proj = (const float*)d_in[4];
  const float* qw     = (const float*)d_in[5];
  const float* kw     = (const float*)d_in[6];
  float* out = (float*)d_out;

  // ws layout (u16 units): xb dead after qkv GEMM -> attn aliases it.
  u16* xb     = (u16*)d_ws;                         //  8388608 elems
  u16* wqkvb  = xb     + (size_t) 8388608;          //  3145728
  u16* wprojb = wqkvb  + (size_t) 3145728;          //  1048576
  u16* qkv    = wprojb + (size_t) 1048576;          // 25165824
  u16* attn   = xb;                                 //  8388608 (alias)

  cvt_bf16<<<2048, 256, 0, stream>>>(x,      xb,     1048576);
  cvt_bf16<<<1536, 256, 0, stream>>>(w_qkv,  wqkvb,   393216);
  cvt_bf16<<< 512, 256, 0, stream>>>(w_proj, wprojb,  131072);

  gemm_bt<2><<<1536, 256, 0, stream>>>(xb, wqkvb, qkv, 8192, 3072, 1024,
                                       cosT, sinT, qw, kw);
  fattn   <<<1024, 256, 0, stream>>>(qkv, attn);
  gemm_bt<1><<<512, 256, 0, stream>>>(attn, wprojb, out, 8192, 1024, 1024,
                                      nullptr, nullptr, nullptr, nullptr);
}

// Round 12
// 180.521 us; speedup vs baseline: 1.2803x; 1.0447x over previous
//
#include <hip/hip_runtime.h>
#include <hip/hip_bf16.h>
#include <stdint.h>

typedef uint16_t u16;
typedef uint32_t u32;
typedef __attribute__((ext_vector_type(8))) short bv8;    // 8 x bf16 (i16 bits), 4 VGPR
typedef __attribute__((ext_vector_type(4))) float f32x4;
typedef __attribute__((ext_vector_type(16))) float f32x16;
typedef __attribute__((ext_vector_type(2))) u32 u32x2;

#define MFMA(a,b,c)   __builtin_amdgcn_mfma_f32_16x16x32_bf16((a),(b),(c),0,0,0)
#define MFMA32(a,b,c) __builtin_amdgcn_mfma_f32_32x32x16_bf16((a),(b),(c),0,0,0)

__device__ __forceinline__ float bf2f(u16 v){ u32 x=(u32)v<<16; float f; __builtin_memcpy(&f,&x,4); return f; }
__device__ __forceinline__ u16 f2bf(float f){ u32 x; __builtin_memcpy(&x,&f,4); x += 0x7fffu + ((x>>16)&1u); return (u16)(x>>16); }
__device__ __forceinline__ u32 cvtpk_bf16(float lo, float hi){
  u32 r; asm("v_cvt_pk_bf16_f32 %0, %1, %2" : "=v"(r) : "v"(lo), "v"(hi)); return r;
}
__device__ __forceinline__ float exp2_fast(float x){
  float r; asm("v_exp_f32 %0, %1" : "=v"(r) : "v"(x)); return r;
}

__device__ __forceinline__ void gl_lds16(const u16* g, u16* l){
  __builtin_amdgcn_global_load_lds((const __attribute__((address_space(1))) u32*)g,
                                   (__attribute__((address_space(3))) u32*)l, 16, 0, 0);
}

// fp32 -> bf16 convert. n8 = elements/8.
__global__ __launch_bounds__(256) void cvt_bf16(const float* __restrict__ src, u16* __restrict__ dst, long n8){
  long i = (long)blockIdx.x*256 + threadIdx.x;
  long stride = (long)gridDim.x*256;
  for(; i<n8; i+=stride){
    f32x4 a = *(const f32x4*)(src + i*8);
    f32x4 b = *(const f32x4*)(src + i*8 + 4);
    bv8 o;
    #pragma unroll
    for(int j=0;j<4;j++) o[j]   = (short)f2bf(a[j]);
    #pragma unroll
    for(int j=0;j<4;j++) o[4+j] = (short)f2bf(b[j]);
    *(bv8*)(dst + i*8) = o;
  }
}

// ---------------------------------------------------------------------------
// C[m,n] = sum_k A[m,k] * B[n,k]   (A: MxK bf16 row-major, B: NxK bf16)
// 128x128 tile, BK=64, 4 waves, global_load_lds w/ pre-swizzled src.
// MODE 0: bf16 out. MODE 1: fp32 out. MODE 2: bf16 out + fused RMSNorm+RoPE
// on q/k column range (qkv GEMM; col-tile never straddles q/k/v; wave
// subtile = one head of 64 dims).
// ---------------------------------------------------------------------------
template<int MODE>
__global__ __launch_bounds__(256,2) void gemm_bt(const u16* __restrict__ A, const u16* __restrict__ B,
                                                 void* __restrict__ Cv, int M, int N, int K,
                                                 const float* __restrict__ cosT,
                                                 const float* __restrict__ sinT,
                                                 const float* __restrict__ qw,
                                                 const float* __restrict__ kw){
  __shared__ __align__(16) u16 As[128*64];
  __shared__ __align__(16) u16 Bs[128*64];
  int nwg = gridDim.x;
  int wg  = (int)blockIdx.x;
  wg = (wg & 7)*(nwg>>3) + (wg>>3);          // XCD swizzle (nwg % 8 == 0)
  int nn = N>>7;
  int tm = wg/nn, tn = wg - tm*nn;
  int rowbase = tm<<7, colbase = tn<<7;
  int t = threadIdx.x, lane = t&63, w = t>>6;
  int g = lane>>4, q16 = lane&15;
  int wr = w>>1, wc = w&1;

  f32x4 z = {0.f,0.f,0.f,0.f};
  f32x4 acc[4][4];
  #pragma unroll
  for(int i=0;i<4;i++)
    #pragma unroll
    for(int j=0;j<4;j++) acc[i][j]=z;

  for(int k0=0;k0<K;k0+=64){
    __syncthreads();
    #pragma unroll
    for(int i=0;i<4;i++){
      int s = ((w<<2)+i)*64 + lane;
      int row = s>>3;
      int ksl = (s&7) ^ (row&7);
      gl_lds16(A + (size_t)(rowbase+row)*K + k0 + ksl*8, (u16*)As + ((w<<2)+i)*512);
      gl_lds16(B + (size_t)(colbase+row)*K + k0 + ksl*8, (u16*)Bs + ((w<<2)+i)*512);
    }
    __syncthreads();
    #pragma unroll
    for(int eks=0;eks<2;eks++){
      bv8 af[4], bfr[4];
      #pragma unroll
      for(int mi=0;mi<4;mi++){
        int row = (wr<<6)+(mi<<4)+q16;
        af[mi] = *(const bv8*)(As + row*64 + ((((eks<<2)|g) ^ (row&7))<<3));
      }
      #pragma unroll
      for(int ni=0;ni<4;ni++){
        int row = (wc<<6)+(ni<<4)+q16;
        bfr[ni] = *(const bv8*)(Bs + row*64 + ((((eks<<2)|g) ^ (row&7))<<3));
      }
      #pragma unroll
      for(int mi=0;mi<4;mi++)
        #pragma unroll
        for(int ni=0;ni<4;ni++)
          acc[mi][ni] = MFMA(af[mi], bfr[ni], acc[mi][ni]);
    }
  }

  if(MODE==2 && colbase < 2048){
    // fused RMSNorm + RoPE (+ q pre-scale 0.125*log2e) on this q/k head
    int s = colbase>>10;                       // 0=q, 1=k
    const float* wsel = s ? kw : qw;
    int ch = colbase + (wc<<6);
    float qsc = s ? 1.0f : 0.1803368801111437f;
    float wv[4];
    #pragma unroll
    for(int ni=0;ni<4;ni++) wv[ni] = wsel[(ni<<4)|q16];
    #pragma unroll
    for(int mi=0;mi<4;mi++){
      #pragma unroll
      for(int r=0;r<4;r++){
        int row = rowbase + (wr<<6)+(mi<<4)+(g<<2)+r;
        int l = row & 1023;
        float y[4];
        float ss = 0.f;
        #pragma unroll
        for(int ni=0;ni<4;ni++){ y[ni]=acc[mi][ni][r]; ss += y[ni]*y[ni]; }
        ss += __shfl_xor(ss,1,64); ss += __shfl_xor(ss,2,64);
        ss += __shfl_xor(ss,4,64); ss += __shfl_xor(ss,8,64);
        float nrm = rsqrtf(ss*(1.f/64.f) + 1e-6f);
        #pragma unroll
        for(int ni=0;ni<4;ni++) y[ni] *= nrm * wv[ni];
        u16* cp = (u16*)Cv + (size_t)row*N + ch;
        #pragma unroll
        for(int ni=0;ni<4;ni++){
          int d = (ni<<4)|q16;
          float rot = (ni<2) ? -y[ni+2] : y[ni-2];  // rotate_half pairing d^32
          float o = (y[ni]*cosT[l*64+d] + rot*sinT[l*64+d]) * qsc;
          cp[d] = f2bf(o);
        }
      }
    }
    return;
  }

  #pragma unroll
  for(int mi=0;mi<4;mi++){
    #pragma unroll
    for(int ni=0;ni<4;ni++){
      int row = rowbase + (wr<<6) + (mi<<4) + (g<<2);
      int col = colbase + (wc<<6) + (ni<<4) + q16;
      if(MODE==1){
        float* cp = (float*)Cv + (size_t)row*N + col;
        #pragma unroll
        for(int r=0;r<4;r++) cp[(size_t)r*N] = acc[mi][ni][r];
      } else {
        u16* cp = (u16*)Cv + (size_t)row*N + col;
        #pragma unroll
        for(int r=0;r<4;r++) cp[(size_t)r*N] = f2bf(acc[mi][ni][r]);
      }
    }
  }
}

// ---------------------------------------------------------------------------
// Flash attention, 32x32x16 MFMA. 8 waves x 32 q-rows (BQ=256 per block),
// KV tile 128 as 2 sub-rounds of 64 kv. Per-wave code = R9/R11-validated.
// K/V staging SHARED across all 8 waves (amortized 2x vs R11): K dbuf DMA
// (2 instr/wave), V^T staged by threads 0-255 (R7-validated geometry).
// Grid 512 = exactly 2 blocks/CU, all resident, zero tail.
// ---------------------------------------------------------------------------
__global__ __launch_bounds__(512,1) void fattn(const u16* __restrict__ qkv, u16* __restrict__ Out){
  __shared__ __align__(16) u16 Ks0[128*64];     // 16KB [kv][e], slot^=(kv&7)
  __shared__ __align__(16) u16 Ks1[128*64];     // 16KB
  __shared__ __align__(16) u16 Vt[64*128];      // 16KB [d][kv], slot^=(d&15)

  int t = threadIdx.x, lane = t&63, w = t>>6;   // w in 0..7
  int ql = lane&31, h = lane>>5;
  int nwg = gridDim.x;
  int bid = (int)blockIdx.x;
  bid = (bid & 7)*(nwg>>3) + (bid>>3);          // XCD swizzle (nwg=512)
  int bh = bid >> 2, qt = bid & 3;              // 4 q-supertiles of 256 rows
  int b = bh >> 4, hd = bh & 15;
  const u16* base = qkv + (size_t)b*1024*3072;
  int Qb = (qt<<8) + (w<<5);                    // wave's 32 q-rows

  bv8 qf[4];
  {
    const u16* qp = base + (size_t)(Qb+ql)*3072 + hd*64 + (h<<3);
    qf[0] = *(const bv8*)(qp);
    qf[1] = *(const bv8*)(qp+16);
    qf[2] = *(const bv8*)(qp+32);
    qf[3] = *(const bv8*)(qp+48);
  }
  f32x16 accO0, accO1;
  #pragma unroll
  for(int r=0;r<16;r++){ accO0[r]=0.f; accO1[r]=0.f; }
  float m_run = -1e30f, l_run = 0.f;

  // V staging geometry (threads 0..255, R7/R8-validated)
  bool vstage = (t < 256);
  int d0v = (t&7)<<3;
  int c4  = (t>>3)&31;
  int sV = c4>>1, halfV = c4&1, kvr = c4<<2;
  int d15b = (t&1)<<3;

  bv8 v0,v1,v2,v3;
  const u16* gV0 = base + (size_t)kvr*3072 + 2048 + hd*64 + d0v;

#define LDV(tl) if(vstage){ const u16* gV = gV0 + (size_t)(tl)*393216; \
    v0 = *(const bv8*)(gV);       v1 = *(const bv8*)(gV+3072); \
    v2 = *(const bv8*)(gV+6144);  v3 = *(const bv8*)(gV+9216); }

#define STV() if(vstage){ \
    _Pragma("unroll") \
    for(int i=0;i<8;i++){ \
      int d = d0v + i; \
      u32x2 val; \
      val.x = (u32)(u16)v0[i] | ((u32)(u16)v1[i]<<16); \
      val.y = (u32)(u16)v2[i] | ((u32)(u16)v3[i]<<16); \
      *(u32x2*)(Vt + d*128 + (((sV ^ (d15b+i))<<3) + (halfV<<2))) = val; \
    } }

#define KDMA(tl, buf) { \
    _Pragma("unroll") \
    for(int i=0;i<2;i++){ \
      int si = ((w<<1)+i)*64 + lane; \
      int row = si>>3; \
      int esl = (si&7) ^ (row&7); \
      gl_lds16(base + (size_t)(((tl)<<7)+row)*3072 + 1024 + hd*64 + esl*8, (buf) + ((w<<1)+i)*512); \
    } }

  // prologue: K(0) DMA, V(0) regs
  KDMA(0, (u16*)Ks0);
  LDV(0);

  for(int tile=0; tile<8; ++tile){
    u16* kcur = (tile&1) ? (u16*)Ks1 : (u16*)Ks0;
    u16* knxt = (tile&1) ? (u16*)Ks0 : (u16*)Ks1;
    if(tile>0) __syncthreads();     // all waves done reading Vt & knxt
    STV();                          // write V(tile)
    __syncthreads();                // Vt visible; K(tile) DMA drained
    if(tile<7){
      KDMA(tile+1, knxt);           // DMA overlaps this tile's compute
      LDV(tile+1);                  // regs for next STV
    }

    #pragma unroll
    for(int sub=0; sub<2; ++sub){
      f32x16 s0, s1;
      #pragma unroll
      for(int r=0;r<16;r++){ s0[r]=0.f; s1[r]=0.f; }
      int rowA = (sub<<6) + ql;
      int rowB = rowA + 32;
      __builtin_amdgcn_s_setprio(1);
      #pragma unroll
      for(int s=0;s<4;s++){
        bv8 ka = *(const bv8*)(kcur + rowA*64 + ((((s<<1)|h) ^ (rowA&7))<<3));
        bv8 kb = *(const bv8*)(kcur + rowB*64 + ((((s<<1)|h) ^ (rowB&7))<<3));
        s0 = MFMA32(ka, qf[s], s0);
        s1 = MFMA32(kb, qf[s], s1);
      }
      __builtin_amdgcn_s_setprio(0);

      float rm = -1e30f;
      #pragma unroll
      for(int r=0;r<16;r++){ rm = fmaxf(rm, fmaxf(s0[r], s1[r])); }
      rm = fmaxf(rm, __shfl_xor(rm, 32, 64));
      if(__any(rm > m_run + 8.0f)){         // defer-max
        float mnew = fmaxf(m_run, rm);
        float fac = exp2_fast(m_run - mnew);
        m_run = mnew;
        l_run *= fac;
        #pragma unroll
        for(int r=0;r<16;r++){
          int qs = (r&3) + ((r>>2)<<3) + (h<<2);
          float fr = __shfl(fac, qs, 64);
          accO0[r] *= fr; accO1[r] *= fr;
        }
      }
      float ps = 0.f;
      #pragma unroll
      for(int r=0;r<16;r++){
        float p0 = exp2_fast(s0[r]-m_run); s0[r] = p0;
        float p1 = exp2_fast(s1[r]-m_run); s1[r] = p1;
        ps += p0 + p1;
      }
      ps += __shfl_xor(ps, 32, 64);
      l_run += ps;

      int dsw = ql & 15;
      #pragma unroll
      for(int tt=0; tt<4; ++tt){
        int b0 = (tt&1)<<1;
        float a0,a1,a2,a3,b4,b5,b6,b7;
        if(tt<2){ a0=s0[4*b0+0]; a1=s0[4*b0+1]; a2=s0[4*b0+2]; a3=s0[4*b0+3];
                  b4=s0[4*b0+4]; b5=s0[4*b0+5]; b6=s0[4*b0+6]; b7=s0[4*b0+7]; }
        else    { a0=s1[4*b0+0]; a1=s1[4*b0+1]; a2=s1[4*b0+2]; a3=s1[4*b0+3];
                  b4=s1[4*b0+4]; b5=s1[4*b0+5]; b6=s1[4*b0+6]; b7=s1[4*b0+7]; }
        u32 Wlo0 = cvtpk_bf16(a0,a1), Wlo1 = cvtpk_bf16(a2,a3);
        u32 Whi0 = cvtpk_bf16(b4,b5), Whi1 = cvtpk_bf16(b6,b7);
        u32 X0 = h ? Wlo0 : Whi0;
        u32 X1 = h ? Wlo1 : Whi1;
        u32 x0 = (u32)__shfl_xor((int)X0, 32, 64);
        u32 x1 = (u32)__shfl_xor((int)X1, 32, 64);
        union { u32 u[4]; bv8 v; } pf;
        pf.u[0] = h ? x0 : Wlo0;
        pf.u[1] = h ? x1 : Wlo1;
        pf.u[2] = h ? Whi0 : x0;
        pf.u[3] = h ? Whi1 : x1;
        int vslot = ((sub<<3)+(tt<<1)+h) ^ dsw;
        bv8 vf0 = *(const bv8*)(Vt + ql*128 + (vslot<<3));
        bv8 vf1 = *(const bv8*)(Vt + (32+ql)*128 + (vslot<<3));
        __builtin_amdgcn_s_setprio(1);
        accO0 = MFMA32(pf.v, vf0, accO0);
        accO1 = MFMA32(pf.v, vf1, accO1);
        __builtin_amdgcn_s_setprio(0);
      }
    }
  }
  float linv = 1.f/l_run;
  #pragma unroll
  for(int r=0;r<16;r++){
    int qs = (r&3) + ((r>>2)<<3) + (h<<2);
    float li = __shfl(linv, qs, 64);
    size_t o = (size_t)(b*1024 + Qb + qs)*1024 + hd*64 + ql;
    Out[o]      = f2bf(accO0[r]*li);
    Out[o + 32] = f2bf(accO1[r]*li);
  }
#undef LDV
#undef STV
#undef KDMA
}

extern "C" void kernel_launch(void* const* d_in, const int* in_sizes, int n_in,
                              void* d_out, int out_size, void* d_ws, size_t ws_size,
                              hipStream_t stream) {
  const float* x      = (const float*)d_in[0];
  const float* cosT   = (const float*)d_in[1];
  const float* sinT   = (const float*)d_in[2];
  const float* w_qkv  = (const float*)d_in[3];
  const float* w_proj = (const float*)d_in[4];
  const float* qw     = (const float*)d_in[5];
  const float* kw     = (const float*)d_in[6];
  float* out = (float*)d_out;

  // ws layout (u16 units): xb dead after qkv GEMM -> attn aliases it.
  u16* xb     = (u16*)d_ws;                         //  8388608 elems
  u16* wqkvb  = xb     + (size_t) 8388608;          //  3145728
  u16* wprojb = wqkvb  + (size_t) 3145728;          //  1048576
  u16* qkv    = wprojb + (size_t) 1048576;          // 25165824
  u16* attn   = xb;                                 //  8388608 (alias)

  cvt_bf16<<<2048, 256, 0, stream>>>(x,      xb,     1048576);
  cvt_bf16<<<1536, 256, 0, stream>>>(w_qkv,  wqkvb,   393216);
  cvt_bf16<<< 512, 256, 0, stream>>>(w_proj, wprojb,  131072);

  gemm_bt<2><<<1536, 256, 0, stream>>>(xb, wqkvb, qkv, 8192, 3072, 1024,
                                       cosT, sinT, qw, kw);
  fattn   <<<512, 512, 0, stream>>>(qkv, attn);
  gemm_bt<1><<<512, 256, 0, stream>>>(attn, wprojb, out, 8192, 1024, 1024,
                                      nullptr, nullptr, nullptr, nullptr);
}

// Round 13
// 174.661 us; speedup vs baseline: 1.3233x; 1.0336x over previous
//
#include <hip/hip_runtime.h>
#include <hip/hip_bf16.h>
#include <stdint.h>

typedef uint16_t u16;
typedef uint32_t u32;
typedef __attribute__((ext_vector_type(8))) short bv8;    // 8 x bf16 (i16 bits), 4 VGPR
typedef __attribute__((ext_vector_type(4))) float f32x4;
typedef __attribute__((ext_vector_type(16))) float f32x16;
typedef __attribute__((ext_vector_type(2))) u32 u32x2;

#define MFMA(a,b,c)   __builtin_amdgcn_mfma_f32_16x16x32_bf16((a),(b),(c),0,0,0)
#define MFMA32(a,b,c) __builtin_amdgcn_mfma_f32_32x32x16_bf16((a),(b),(c),0,0,0)

__device__ __forceinline__ float bf2f(u16 v){ u32 x=(u32)v<<16; float f; __builtin_memcpy(&f,&x,4); return f; }
__device__ __forceinline__ u16 f2bf(float f){ u32 x; __builtin_memcpy(&x,&f,4); x += 0x7fffu + ((x>>16)&1u); return (u16)(x>>16); }
__device__ __forceinline__ u32 cvtpk_bf16(float lo, float hi){
  u32 r; asm("v_cvt_pk_bf16_f32 %0, %1, %2" : "=v"(r) : "v"(lo), "v"(hi)); return r;
}
__device__ __forceinline__ float exp2_fast(float x){
  float r; asm("v_exp_f32 %0, %1" : "=v"(r) : "v"(x)); return r;
}
__device__ __forceinline__ float rcp_fast(float x){
  float r; asm("v_rcp_f32 %0, %1" : "=v"(r) : "v"(x)); return r;
}

__device__ __forceinline__ void gl_lds16(const u16* g, u16* l){
  __builtin_amdgcn_global_load_lds((const __attribute__((address_space(1))) u32*)g,
                                   (__attribute__((address_space(3))) u32*)l, 16, 0, 0);
}

// fused fp32 -> bf16 convert of x / w_qkv / w_proj into contiguous ws region.
__global__ __launch_bounds__(256) void cvt3(const float* __restrict__ x, const float* __restrict__ wq,
                                            const float* __restrict__ wp, u16* __restrict__ dst){
  const long NA = 1048576, NB = 393216, NC = 131072;   // n8 per source
  long i = (long)blockIdx.x*256 + threadIdx.x;
  long stride = (long)gridDim.x*256;
  for(; i < NA+NB+NC; i += stride){
    const float* s;
    if(i < NA)            s = x  + i*8;
    else if(i < NA+NB)    s = wq + (i-NA)*8;
    else                  s = wp + (i-NA-NB)*8;
    f32x4 a = *(const f32x4*)(s);
    f32x4 b = *(const f32x4*)(s + 4);
    bv8 o;
    #pragma unroll
    for(int j=0;j<4;j++) o[j]   = (short)f2bf(a[j]);
    #pragma unroll
    for(int j=0;j<4;j++) o[4+j] = (short)f2bf(b[j]);
    *(bv8*)(dst + i*8) = o;
  }
}

// ---------------------------------------------------------------------------
// C[m,n] = sum_k A[m,k] * B[n,k]   (A: MxK bf16 row-major, B: NxK bf16)
// 128x128 tile, BK=64, 4 waves, global_load_lds w/ pre-swizzled src.
// MODE 1: fp32 out. MODE 2: bf16 out + fused RMSNorm+RoPE on q/k cols.
// ---------------------------------------------------------------------------
template<int MODE>
__global__ __launch_bounds__(256,2) void gemm_bt(const u16* __restrict__ A, const u16* __restrict__ B,
                                                 void* __restrict__ Cv, int M, int N, int K,
                                                 const float* __restrict__ cosT,
                                                 const float* __restrict__ sinT,
                                                 const float* __restrict__ qw,
                                                 const float* __restrict__ kw){
  __shared__ __align__(16) u16 As[128*64];
  __shared__ __align__(16) u16 Bs[128*64];
  int nwg = gridDim.x;
  int wg  = (int)blockIdx.x;
  wg = (wg & 7)*(nwg>>3) + (wg>>3);          // XCD swizzle (nwg % 8 == 0)
  int nn = N>>7;
  int tm = wg/nn, tn = wg - tm*nn;
  int rowbase = tm<<7, colbase = tn<<7;
  int t = threadIdx.x, lane = t&63, w = t>>6;
  int g = lane>>4, q16 = lane&15;
  int wr = w>>1, wc = w&1;

  f32x4 z = {0.f,0.f,0.f,0.f};
  f32x4 acc[4][4];
  #pragma unroll
  for(int i=0;i<4;i++)
    #pragma unroll
    for(int j=0;j<4;j++) acc[i][j]=z;

  for(int k0=0;k0<K;k0+=64){
    __syncthreads();
    #pragma unroll
    for(int i=0;i<4;i++){
      int s = ((w<<2)+i)*64 + lane;
      int row = s>>3;
      int ksl = (s&7) ^ (row&7);
      gl_lds16(A + (size_t)(rowbase+row)*K + k0 + ksl*8, (u16*)As + ((w<<2)+i)*512);
      gl_lds16(B + (size_t)(colbase+row)*K + k0 + ksl*8, (u16*)Bs + ((w<<2)+i)*512);
    }
    __syncthreads();
    #pragma unroll
    for(int eks=0;eks<2;eks++){
      bv8 af[4], bfr[4];
      #pragma unroll
      for(int mi=0;mi<4;mi++){
        int row = (wr<<6)+(mi<<4)+q16;
        af[mi] = *(const bv8*)(As + row*64 + ((((eks<<2)|g) ^ (row&7))<<3));
      }
      #pragma unroll
      for(int ni=0;ni<4;ni++){
        int row = (wc<<6)+(ni<<4)+q16;
        bfr[ni] = *(const bv8*)(Bs + row*64 + ((((eks<<2)|g) ^ (row&7))<<3));
      }
      #pragma unroll
      for(int mi=0;mi<4;mi++)
        #pragma unroll
        for(int ni=0;ni<4;ni++)
          acc[mi][ni] = MFMA(af[mi], bfr[ni], acc[mi][ni]);
    }
  }

  if(MODE==2 && colbase < 2048){
    // fused RMSNorm + RoPE (+ q pre-scale 0.125*log2e) on this q/k head
    int s = colbase>>10;                       // 0=q, 1=k
    const float* wsel = s ? kw : qw;
    int ch = colbase + (wc<<6);
    float qsc = s ? 1.0f : 0.1803368801111437f;
    float wv[4];
    #pragma unroll
    for(int ni=0;ni<4;ni++) wv[ni] = wsel[(ni<<4)|q16];
    #pragma unroll
    for(int mi=0;mi<4;mi++){
      #pragma unroll
      for(int r=0;r<4;r++){
        int row = rowbase + (wr<<6)+(mi<<4)+(g<<2)+r;
        int l = row & 1023;
        float y[4];
        float ss = 0.f;
        #pragma unroll
        for(int ni=0;ni<4;ni++){ y[ni]=acc[mi][ni][r]; ss += y[ni]*y[ni]; }
        ss += __shfl_xor(ss,1,64); ss += __shfl_xor(ss,2,64);
        ss += __shfl_xor(ss,4,64); ss += __shfl_xor(ss,8,64);
        float nrm = rsqrtf(ss*(1.f/64.f) + 1e-6f);
        #pragma unroll
        for(int ni=0;ni<4;ni++) y[ni] *= nrm * wv[ni];
        u16* cp = (u16*)Cv + (size_t)row*N + ch;
        #pragma unroll
        for(int ni=0;ni<4;ni++){
          int d = (ni<<4)|q16;
          float rot = (ni<2) ? -y[ni+2] : y[ni-2];  // rotate_half pairing d^32
          float o = (y[ni]*cosT[l*64+d] + rot*sinT[l*64+d]) * qsc;
          cp[d] = f2bf(o);
        }
      }
    }
    return;
  }

  #pragma unroll
  for(int mi=0;mi<4;mi++){
    #pragma unroll
    for(int ni=0;ni<4;ni++){
      int row = rowbase + (wr<<6) + (mi<<4) + (g<<2);
      int col = colbase + (wc<<6) + (ni<<4) + q16;
      if(MODE==1){
        float* cp = (float*)Cv + (size_t)row*N + col;
        #pragma unroll
        for(int r=0;r<4;r++) cp[(size_t)r*N] = acc[mi][ni][r];
      } else {
        u16* cp = (u16*)Cv + (size_t)row*N + col;
        #pragma unroll
        for(int r=0;r<4;r++) cp[(size_t)r*N] = f2bf(acc[mi][ni][r]);
      }
    }
  }
}

// ---------------------------------------------------------------------------
// Flash attention, 32x32x16 MFMA. 8 waves x 32 q-rows (BQ=256/block).
// SINGLE barrier/tile: K AND V both double-buffered; tile t reads buf[t&1],
// writes buf[(t+1)&1] (= the buffer tile t-1 read -> safe after barrier).
// Softmax denominator via ones-MFMA into accL (same layout/rescale as accO);
// epilogue divides lane-locally (v_rcp), no shuffles. Defer-max (T13).
// ---------------------------------------------------------------------------
__global__ __launch_bounds__(512,1) void fattn(const u16* __restrict__ qkv, u16* __restrict__ Out){
  __shared__ __align__(16) u16 Ks0[128*64];     // 16KB [kv][e], slot^=(kv&7)
  __shared__ __align__(16) u16 Ks1[128*64];     // 16KB
  __shared__ __align__(16) u16 Vt[2][64*128];   // 2x16KB [d][kv], slot^=(d&15)

  int t = threadIdx.x, lane = t&63, w = t>>6;   // w in 0..7
  int ql = lane&31, h = lane>>5;
  int nwg = gridDim.x;
  int bid = (int)blockIdx.x;
  bid = (bid & 7)*(nwg>>3) + (bid>>3);          // XCD swizzle (nwg=512)
  int bh = bid >> 2, qt = bid & 3;              // 4 q-supertiles of 256 rows
  int b = bh >> 4, hd = bh & 15;
  const u16* base = qkv + (size_t)b*1024*3072;
  int Qb = (qt<<8) + (w<<5);                    // wave's 32 q-rows

  bv8 qf[4];
  {
    const u16* qp = base + (size_t)(Qb+ql)*3072 + hd*64 + (h<<3);
    qf[0] = *(const bv8*)(qp);
    qf[1] = *(const bv8*)(qp+16);
    qf[2] = *(const bv8*)(qp+32);
    qf[3] = *(const bv8*)(qp+48);
  }
  bv8 onesb;
  #pragma unroll
  for(int j=0;j<8;j++) onesb[j] = (short)0x3F80;   // bf16 1.0

  f32x16 accO0, accO1, accL;
  #pragma unroll
  for(int r=0;r<16;r++){ accO0[r]=0.f; accO1[r]=0.f; accL[r]=0.f; }
  float m_run = -1e30f;

  // V staging geometry (threads 0..255, validated)
  bool vstage = (t < 256);
  int d0v = (t&7)<<3;
  int c4  = (t>>3)&31;
  int sV = c4>>1, halfV = c4&1, kvr = c4<<2;
  int d15b = (t&1)<<3;

  bv8 v0,v1,v2,v3;
  const u16* gV0 = base + (size_t)kvr*3072 + 2048 + hd*64 + d0v;

#define LDV(tl) if(vstage){ const u16* gV = gV0 + (size_t)(tl)*393216; \
    v0 = *(const bv8*)(gV);       v1 = *(const bv8*)(gV+3072); \
    v2 = *(const bv8*)(gV+6144);  v3 = *(const bv8*)(gV+9216); }

#define STV(buf) if(vstage){ \
    _Pragma("unroll") \
    for(int i=0;i<8;i++){ \
      int d = d0v + i; \
      u32x2 val; \
      val.x = (u32)(u16)v0[i] | ((u32)(u16)v1[i]<<16); \
      val.y = (u32)(u16)v2[i] | ((u32)(u16)v3[i]<<16); \
      *(u32x2*)((buf) + d*128 + (((sV ^ (d15b+i))<<3) + (halfV<<2))) = val; \
    } }

#define KDMA(tl, buf) { \
    _Pragma("unroll") \
    for(int i=0;i<2;i++){ \
      int si = ((w<<1)+i)*64 + lane; \
      int row = si>>3; \
      int esl = (si&7) ^ (row&7); \
      gl_lds16(base + (size_t)(((tl)<<7)+row)*3072 + 1024 + hd*64 + esl*8, (buf) + ((w<<1)+i)*512); \
    } }

  // prologue: K(0) DMA; V(0) -> Vt[0]; V(1) regs
  KDMA(0, (u16*)Ks0);
  LDV(0);
  STV(Vt[0]);
  LDV(1);

  for(int tile=0; tile<8; ++tile){
    u16* kcur = (tile&1) ? (u16*)Ks1 : (u16*)Ks0;
    u16* knxt = (tile&1) ? (u16*)Ks0 : (u16*)Ks1;
    u16* vcur = Vt[tile&1];
    u16* vnxt = Vt[(tile&1)^1];
    __syncthreads();                // buf(tile) ready; buf(tile+1) free to write
    if(tile<7){
      KDMA(tile+1, knxt);           // DMA overlaps compute
      STV(vnxt);                    // write V(tile+1) from prefetched regs
    }
    if(tile<6) LDV(tile+2);         // prefetch V(tile+2) regs

    #pragma unroll
    for(int sub=0; sub<2; ++sub){
      f32x16 s0, s1;
      #pragma unroll
      for(int r=0;r<16;r++){ s0[r]=0.f; s1[r]=0.f; }
      int rowA = (sub<<6) + ql;
      int rowB = rowA + 32;
      __builtin_amdgcn_s_setprio(1);
      #pragma unroll
      for(int s=0;s<4;s++){
        bv8 ka = *(const bv8*)(kcur + rowA*64 + ((((s<<1)|h) ^ (rowA&7))<<3));
        bv8 kb = *(const bv8*)(kcur + rowB*64 + ((((s<<1)|h) ^ (rowB&7))<<3));
        s0 = MFMA32(ka, qf[s], s0);
        s1 = MFMA32(kb, qf[s], s1);
      }
      __builtin_amdgcn_s_setprio(0);

      float rm = -1e30f;
      #pragma unroll
      for(int r=0;r<16;r++){ rm = fmaxf(rm, fmaxf(s0[r], s1[r])); }
      rm = fmaxf(rm, __shfl_xor(rm, 32, 64));
      if(__any(rm > m_run + 8.0f)){         // defer-max
        float mnew = fmaxf(m_run, rm);
        float fac = exp2_fast(m_run - mnew);
        m_run = mnew;
        #pragma unroll
        for(int r=0;r<16;r++){
          int qs = (r&3) + ((r>>2)<<3) + (h<<2);
          float fr = __shfl(fac, qs, 64);
          accO0[r] *= fr; accO1[r] *= fr; accL[r] *= fr;
        }
      }
      #pragma unroll
      for(int r=0;r<16;r++){
        s0[r] = exp2_fast(s0[r]-m_run);
        s1[r] = exp2_fast(s1[r]-m_run);
      }

      int dsw = ql & 15;
      #pragma unroll
      for(int tt=0; tt<4; ++tt){
        int b0 = (tt&1)<<1;
        float a0,a1,a2,a3,b4,b5,b6,b7;
        if(tt<2){ a0=s0[4*b0+0]; a1=s0[4*b0+1]; a2=s0[4*b0+2]; a3=s0[4*b0+3];
                  b4=s0[4*b0+4]; b5=s0[4*b0+5]; b6=s0[4*b0+6]; b7=s0[4*b0+7]; }
        else    { a0=s1[4*b0+0]; a1=s1[4*b0+1]; a2=s1[4*b0+2]; a3=s1[4*b0+3];
                  b4=s1[4*b0+4]; b5=s1[4*b0+5]; b6=s1[4*b0+6]; b7=s1[4*b0+7]; }
        u32 Wlo0 = cvtpk_bf16(a0,a1), Wlo1 = cvtpk_bf16(a2,a3);
        u32 Whi0 = cvtpk_bf16(b4,b5), Whi1 = cvtpk_bf16(b6,b7);
        u32 X0 = h ? Wlo0 : Whi0;
        u32 X1 = h ? Wlo1 : Whi1;
        u32 x0 = (u32)__shfl_xor((int)X0, 32, 64);
        u32 x1 = (u32)__shfl_xor((int)X1, 32, 64);
        union { u32 u[4]; bv8 v; } pf;
        pf.u[0] = h ? x0 : Wlo0;
        pf.u[1] = h ? x1 : Wlo1;
        pf.u[2] = h ? Whi0 : x0;
        pf.u[3] = h ? Whi1 : x1;
        int vslot = ((sub<<3)+(tt<<1)+h) ^ dsw;
        bv8 vf0 = *(const bv8*)(vcur + ql*128 + (vslot<<3));
        bv8 vf1 = *(const bv8*)(vcur + (32+ql)*128 + (vslot<<3));
        __builtin_amdgcn_s_setprio(1);
        accO0 = MFMA32(pf.v, vf0, accO0);
        accO1 = MFMA32(pf.v, vf1, accO1);
        accL  = MFMA32(pf.v, onesb, accL);   // denominator rowsum (all cols equal)
        __builtin_amdgcn_s_setprio(0);
      }
    }
  }
  // epilogue: lane-local divide (accL[r] = rowsum for this r's q-row)
  #pragma unroll
  for(int r=0;r<16;r++){
    int qs = (r&3) + ((r>>2)<<3) + (h<<2);
    float li = rcp_fast(accL[r]);
    size_t o = (size_t)(b*1024 + Qb + qs)*1024 + hd*64 + ql;
    Out[o]      = f2bf(accO0[r]*li);
    Out[o + 32] = f2bf(accO1[r]*li);
  }
#undef LDV
#undef STV
#undef KDMA
}

extern "C" void kernel_launch(void* const* d_in, const int* in_sizes, int n_in,
                              void* d_out, int out_size, void* d_ws, size_t ws_size,
                              hipStream_t stream) {
  const float* x      = (const float*)d_in[0];
  const float* cosT   = (const float*)d_in[1];
  const float* sinT   = (const float*)d_in[2];
  const float* w_qkv  = (const float*)d_in[3];
  const float* w_proj = (const float*)d_in[4];
  const float* qw     = (const float*)d_in[5];
  const float* kw     = (const float*)d_in[6];
  float* out = (float*)d_out;

  // ws layout (u16 units): xb dead after qkv GEMM -> attn aliases it.
  u16* xb     = (u16*)d_ws;                         //  8388608 elems
  u16* wqkvb  = xb     + (size_t) 8388608;          //  3145728
  u16* wprojb = wqkvb  + (size_t) 3145728;          //  1048576
  u16* qkv    = wprojb + (size_t) 1048576;          // 25165824
  u16* attn   = xb;                                 //  8388608 (alias)

  cvt3<<<3072, 256, 0, stream>>>(x, w_qkv, w_proj, xb);

  gemm_bt<2><<<1536, 256, 0, stream>>>(xb, wqkvb, qkv, 8192, 3072, 1024,
                                       cosT, sinT, qw, kw);
  fattn   <<<512, 512, 0, stream>>>(qkv, attn);
  gemm_bt<1><<<512, 256, 0, stream>>>(attn, wprojb, out, 8192, 1024, 1024,
                                      nullptr, nullptr, nullptr, nullptr);
}

// Round 15
// 170.699 us; speedup vs baseline: 1.3540x; 1.0232x over previous
//
#include <hip/hip_runtime.h>
#include <hip/hip_bf16.h>
#include <stdint.h>

typedef uint16_t u16;
typedef uint32_t u32;
typedef __attribute__((ext_vector_type(8))) short bv8;    // 8 x bf16 (i16 bits), 4 VGPR
typedef __attribute__((ext_vector_type(4))) float f32x4;
typedef __attribute__((ext_vector_type(16))) float f32x16;
typedef __attribute__((ext_vector_type(2))) u32 u32x2;

#define MFMA(a,b,c)   __builtin_amdgcn_mfma_f32_16x16x32_bf16((a),(b),(c),0,0,0)
#define MFMA32(a,b,c) __builtin_amdgcn_mfma_f32_32x32x16_bf16((a),(b),(c),0,0,0)

__device__ __forceinline__ float bf2f(u16 v){ u32 x=(u32)v<<16; float f; __builtin_memcpy(&f,&x,4); return f; }
__device__ __forceinline__ u16 f2bf(float f){ u32 x; __builtin_memcpy(&x,&f,4); x += 0x7fffu + ((x>>16)&1u); return (u16)(x>>16); }
__device__ __forceinline__ u32 cvtpk_bf16(float lo, float hi){
  u32 r; asm("v_cvt_pk_bf16_f32 %0, %1, %2" : "=v"(r) : "v"(lo), "v"(hi)); return r;
}
__device__ __forceinline__ float exp2_fast(float x){
  float r; asm("v_exp_f32 %0, %1" : "=v"(r) : "v"(x)); return r;
}
__device__ __forceinline__ float rcp_fast(float x){
  float r; asm("v_rcp_f32 %0, %1" : "=v"(r) : "v"(x)); return r;
}

__device__ __forceinline__ void gl_lds16(const u16* g, u16* l){
  __builtin_amdgcn_global_load_lds((const __attribute__((address_space(1))) u32*)g,
                                   (__attribute__((address_space(3))) u32*)l, 16, 0, 0);
}

// fused fp32 -> bf16 convert of x / w_qkv / w_proj into contiguous ws region.
__global__ __launch_bounds__(256) void cvt3(const float* __restrict__ x, const float* __restrict__ wq,
                                            const float* __restrict__ wp, u16* __restrict__ dst){
  const long NA = 1048576, NB = 393216, NC = 131072;   // n8 per source
  long i = (long)blockIdx.x*256 + threadIdx.x;
  long stride = (long)gridDim.x*256;
  for(; i < NA+NB+NC; i += stride){
    const float* s;
    if(i < NA)            s = x  + i*8;
    else if(i < NA+NB)    s = wq + (i-NA)*8;
    else                  s = wp + (i-NA-NB)*8;
    f32x4 a = *(const f32x4*)(s);
    f32x4 b = *(const f32x4*)(s + 4);
    bv8 o;
    #pragma unroll
    for(int j=0;j<4;j++) o[j]   = (short)f2bf(a[j]);
    #pragma unroll
    for(int j=0;j<4;j++) o[4+j] = (short)f2bf(b[j]);
    *(bv8*)(dst + i*8) = o;
  }
}

// ---------------------------------------------------------------------------
// C[m,n] = sum_k A[m,k] * B[n,k]   (A: MxK bf16 row-major, B: NxK bf16)
// 128x128 tile, BK=64, 4 waves, global_load_lds w/ pre-swizzled src.
// MODE 1: fp32 out. MODE 2: bf16 out + fused RMSNorm+RoPE on q/k cols.
// ---------------------------------------------------------------------------
template<int MODE>
__global__ __launch_bounds__(256,2) void gemm_bt(const u16* __restrict__ A, const u16* __restrict__ B,
                                                 void* __restrict__ Cv, int M, int N, int K,
                                                 const float* __restrict__ cosT,
                                                 const float* __restrict__ sinT,
                                                 const float* __restrict__ qw,
                                                 const float* __restrict__ kw){
  __shared__ __align__(16) u16 As[128*64];
  __shared__ __align__(16) u16 Bs[128*64];
  int nwg = gridDim.x;
  int wg  = (int)blockIdx.x;
  wg = (wg & 7)*(nwg>>3) + (wg>>3);          // XCD swizzle (nwg % 8 == 0)
  int nn = N>>7;
  int tm = wg/nn, tn = wg - tm*nn;
  int rowbase = tm<<7, colbase = tn<<7;
  int t = threadIdx.x, lane = t&63, w = t>>6;
  int g = lane>>4, q16 = lane&15;
  int wr = w>>1, wc = w&1;

  f32x4 z = {0.f,0.f,0.f,0.f};
  f32x4 acc[4][4];
  #pragma unroll
  for(int i=0;i<4;i++)
    #pragma unroll
    for(int j=0;j<4;j++) acc[i][j]=z;

  for(int k0=0;k0<K;k0+=64){
    __syncthreads();
    #pragma unroll
    for(int i=0;i<4;i++){
      int s = ((w<<2)+i)*64 + lane;
      int row = s>>3;
      int ksl = (s&7) ^ (row&7);
      gl_lds16(A + (size_t)(rowbase+row)*K + k0 + ksl*8, (u16*)As + ((w<<2)+i)*512);
      gl_lds16(B + (size_t)(colbase+row)*K + k0 + ksl*8, (u16*)Bs + ((w<<2)+i)*512);
    }
    __syncthreads();
    #pragma unroll
    for(int eks=0;eks<2;eks++){
      bv8 af[4], bfr[4];
      #pragma unroll
      for(int mi=0;mi<4;mi++){
        int row = (wr<<6)+(mi<<4)+q16;
        af[mi] = *(const bv8*)(As + row*64 + ((((eks<<2)|g) ^ (row&7))<<3));
      }
      #pragma unroll
      for(int ni=0;ni<4;ni++){
        int row = (wc<<6)+(ni<<4)+q16;
        bfr[ni] = *(const bv8*)(Bs + row*64 + ((((eks<<2)|g) ^ (row&7))<<3));
      }
      #pragma unroll
      for(int mi=0;mi<4;mi++)
        #pragma unroll
        for(int ni=0;ni<4;ni++)
          acc[mi][ni] = MFMA(af[mi], bfr[ni], acc[mi][ni]);
    }
  }

  if(MODE==2 && colbase < 2048){
    // fused RMSNorm + RoPE (+ q pre-scale 0.125*log2e) on this q/k head
    int s = colbase>>10;                       // 0=q, 1=k
    const float* wsel = s ? kw : qw;
    int ch = colbase + (wc<<6);
    float qsc = s ? 1.0f : 0.1803368801111437f;
    float wv[4];
    #pragma unroll
    for(int ni=0;ni<4;ni++) wv[ni] = wsel[(ni<<4)|q16];
    #pragma unroll
    for(int mi=0;mi<4;mi++){
      #pragma unroll
      for(int r=0;r<4;r++){
        int row = rowbase + (wr<<6)+(mi<<4)+(g<<2)+r;
        int l = row & 1023;
        float y[4];
        float ss = 0.f;
        #pragma unroll
        for(int ni=0;ni<4;ni++){ y[ni]=acc[mi][ni][r]; ss += y[ni]*y[ni]; }
        ss += __shfl_xor(ss,1,64); ss += __shfl_xor(ss,2,64);
        ss += __shfl_xor(ss,4,64); ss += __shfl_xor(ss,8,64);
        float nrm = rsqrtf(ss*(1.f/64.f) + 1e-6f);
        #pragma unroll
        for(int ni=0;ni<4;ni++) y[ni] *= nrm * wv[ni];
        u16* cp = (u16*)Cv + (size_t)row*N + ch;
        #pragma unroll
        for(int ni=0;ni<4;ni++){
          int d = (ni<<4)|q16;
          float rot = (ni<2) ? -y[ni+2] : y[ni-2];  // rotate_half pairing d^32
          float o = (y[ni]*cosT[l*64+d] + rot*sinT[l*64+d]) * qsc;
          cp[d] = f2bf(o);
        }
      }
    }
    return;
  }

  #pragma unroll
  for(int mi=0;mi<4;mi++){
    #pragma unroll
    for(int ni=0;ni<4;ni++){
      int row = rowbase + (wr<<6) + (mi<<4) + (g<<2);
      int col = colbase + (wc<<6) + (ni<<4) + q16;
      if(MODE==1){
        float* cp = (float*)Cv + (size_t)row*N + col;
        #pragma unroll
        for(int r=0;r<4;r++) cp[(size_t)r*N] = acc[mi][ni][r];
      } else {
        u16* cp = (u16*)Cv + (size_t)row*N + col;
        #pragma unroll
        for(int r=0;r<4;r++) cp[(size_t)r*N] = f2bf(acc[mi][ni][r]);
      }
    }
  }
}

// ---------------------------------------------------------------------------
// Flash attention, 32x32x16 MFMA. 8 waves x 32 q-rows (BQ=256/block).
// R13-validated structure (online max + defer (T13), accL ones-MFMA
// denominator, single barrier/tile, K+V double-buffered) plus:
//  - Vt swizzle f(d) = (d&15) ^ (((d>>4)&3)<<1): injects d bits 4-5 into
//    bank bits -> STV ds_write_b64 conflicts 8-way -> 4-way (b64 floor).
//    Applied on BOTH write and read sides; read multiplicity unchanged.
//  - STV/LDV moved after sub-0 QK^T: V writes drain during softmax VALU
//    phase instead of contending with QK^T ds_reads.
// ---------------------------------------------------------------------------
__global__ __launch_bounds__(512,1) void fattn(const u16* __restrict__ qkv, u16* __restrict__ Out){
  __shared__ __align__(16) u16 Ks0[128*64];     // 16KB [kv][e], slot^=(kv&7)
  __shared__ __align__(16) u16 Ks1[128*64];     // 16KB
  __shared__ __align__(16) u16 Vt[2][64*128];   // 2x16KB [d][kv], slot = chunk ^ f(d)

  int t = threadIdx.x, lane = t&63, w = t>>6;   // w in 0..7
  int ql = lane&31, h = lane>>5;
  int nwg = gridDim.x;
  int bid = (int)blockIdx.x;
  bid = (bid & 7)*(nwg>>3) + (bid>>3);          // XCD swizzle (nwg=512)
  int bh = bid >> 2, qt = bid & 3;              // 4 q-supertiles of 256 rows
  int b = bh >> 4, hd = bh & 15;
  const u16* base = qkv + (size_t)b*1024*3072;
  int Qb = (qt<<8) + (w<<5);                    // wave's 32 q-rows

  bv8 qf[4];
  {
    const u16* qp = base + (size_t)(Qb+ql)*3072 + hd*64 + (h<<3);
    qf[0] = *(const bv8*)(qp);
    qf[1] = *(const bv8*)(qp+16);
    qf[2] = *(const bv8*)(qp+32);
    qf[3] = *(const bv8*)(qp+48);
  }
  bv8 onesb;
  #pragma unroll
  for(int j=0;j<8;j++) onesb[j] = (short)0x3F80;   // bf16 1.0

  f32x16 accO0, accO1, accL;
  #pragma unroll
  for(int r=0;r<16;r++){ accO0[r]=0.f; accO1[r]=0.f; accL[r]=0.f; }
  float m_run = -1e30f;

  // V staging geometry (threads 0..255, validated)
  bool vstage = (t < 256);
  int d0v = (t&7)<<3;
  int c4  = (t>>3)&31;
  int sV = c4>>1, halfV = c4&1, kvr = c4<<2;
  int d15b = (t&1)<<3;
  int vxt  = ((t>>1)&3)<<1;                     // ((d>>4)&3)<<1, d = (t&7)*8+i

  bv8 v0,v1,v2,v3;
  const u16* gV0 = base + (size_t)kvr*3072 + 2048 + hd*64 + d0v;

#define LDV(tl) if(vstage){ const u16* gV = gV0 + (size_t)(tl)*393216; \
    v0 = *(const bv8*)(gV);       v1 = *(const bv8*)(gV+3072); \
    v2 = *(const bv8*)(gV+6144);  v3 = *(const bv8*)(gV+9216); }

#define STV(buf) if(vstage){ \
    _Pragma("unroll") \
    for(int i=0;i<8;i++){ \
      int d = d0v + i; \
      u32x2 val; \
      val.x = (u32)(u16)v0[i] | ((u32)(u16)v1[i]<<16); \
      val.y = (u32)(u16)v2[i] | ((u32)(u16)v3[i]<<16); \
      *(u32x2*)((buf) + d*128 + ((((sV ^ (d15b+i) ^ vxt))<<3) + (halfV<<2))) = val; \
    } }

#define KDMA(tl, buf) { \
    _Pragma("unroll") \
    for(int i=0;i<2;i++){ \
      int si = ((w<<1)+i)*64 + lane; \
      int row = si>>3; \
      int esl = (si&7) ^ (row&7); \
      gl_lds16(base + (size_t)(((tl)<<7)+row)*3072 + 1024 + hd*64 + esl*8, (buf) + ((w<<1)+i)*512); \
    } }

  // prologue: K(0) DMA; V(0) -> Vt[0]; V(1) regs
  KDMA(0, (u16*)Ks0);
  LDV(0);
  STV(Vt[0]);
  LDV(1);

  int rx0 = (ql>>4)<<1;                         // read-side f(d) term for d=ql
  int dsw = ql & 15;

  for(int tile=0; tile<8; ++tile){
    u16* kcur = (tile&1) ? (u16*)Ks1 : (u16*)Ks0;
    u16* knxt = (tile&1) ? (u16*)Ks0 : (u16*)Ks1;
    u16* vcur = Vt[tile&1];
    u16* vnxt = Vt[(tile&1)^1];
    __syncthreads();                // buf(tile) ready; buf(tile+1) free to write
    if(tile<7) KDMA(tile+1, knxt);  // async DMA overlaps compute

    #pragma unroll
    for(int sub=0; sub<2; ++sub){
      f32x16 s0, s1;
      #pragma unroll
      for(int r=0;r<16;r++){ s0[r]=0.f; s1[r]=0.f; }
      int rowA = (sub<<6) + ql;
      int rowB = rowA + 32;
      __builtin_amdgcn_s_setprio(1);
      #pragma unroll
      for(int s=0;s<4;s++){
        bv8 ka = *(const bv8*)(kcur + rowA*64 + ((((s<<1)|h) ^ (rowA&7))<<3));
        bv8 kb = *(const bv8*)(kcur + rowB*64 + ((((s<<1)|h) ^ (rowB&7))<<3));
        s0 = MFMA32(ka, qf[s], s0);
        s1 = MFMA32(kb, qf[s], s1);
      }
      __builtin_amdgcn_s_setprio(0);

      if(sub==0){
        if(tile<7) STV(vnxt);       // V writes drain during softmax VALU phase
        if(tile<6) LDV(tile+2);     // prefetch V(tile+2) regs
      }

      float rm = -1e30f;
      #pragma unroll
      for(int r=0;r<16;r++){ rm = fmaxf(rm, fmaxf(s0[r], s1[r])); }
      rm = fmaxf(rm, __shfl_xor(rm, 32, 64));
      if(__any(rm > m_run + 8.0f)){         // defer-max (T13)
        float mnew = fmaxf(m_run, rm);
        float fac = exp2_fast(m_run - mnew);
        m_run = mnew;
        #pragma unroll
        for(int r=0;r<16;r++){
          int qs = (r&3) + ((r>>2)<<3) + (h<<2);
          float fr = __shfl(fac, qs, 64);
          accO0[r] *= fr; accO1[r] *= fr; accL[r] *= fr;
        }
      }
      #pragma unroll
      for(int r=0;r<16;r++){
        s0[r] = exp2_fast(s0[r]-m_run);
        s1[r] = exp2_fast(s1[r]-m_run);
      }

      #pragma unroll
      for(int tt=0; tt<4; ++tt){
        int b0 = (tt&1)<<1;
        float a0,a1,a2,a3,b4,b5,b6,b7;
        if(tt<2){ a0=s0[4*b0+0]; a1=s0[4*b0+1]; a2=s0[4*b0+2]; a3=s0[4*b0+3];
                  b4=s0[4*b0+4]; b5=s0[4*b0+5]; b6=s0[4*b0+6]; b7=s0[4*b0+7]; }
        else    { a0=s1[4*b0+0]; a1=s1[4*b0+1]; a2=s1[4*b0+2]; a3=s1[4*b0+3];
                  b4=s1[4*b0+4]; b5=s1[4*b0+5]; b6=s1[4*b0+6]; b7=s1[4*b0+7]; }
        u32 Wlo0 = cvtpk_bf16(a0,a1), Wlo1 = cvtpk_bf16(a2,a3);
        u32 Whi0 = cvtpk_bf16(b4,b5), Whi1 = cvtpk_bf16(b6,b7);
        u32 X0 = h ? Wlo0 : Whi0;
        u32 X1 = h ? Wlo1 : Whi1;
        u32 x0 = (u32)__shfl_xor((int)X0, 32, 64);
        u32 x1 = (u32)__shfl_xor((int)X1, 32, 64);
        union { u32 u[4]; bv8 v; } pf;
        pf.u[0] = h ? x0 : Wlo0;
        pf.u[1] = h ? x1 : Wlo1;
        pf.u[2] = h ? Whi0 : x0;
        pf.u[3] = h ? Whi1 : x1;
        int vslot0 = (((sub<<3)+(tt<<1)+h) ^ dsw ^ rx0);
        bv8 vf0 = *(const bv8*)(vcur + ql*128 + (vslot0<<3));
        bv8 vf1 = *(const bv8*)(vcur + (32+ql)*128 + ((vslot0^4)<<3));
        __builtin_amdgcn_s_setprio(1);
        accO0 = MFMA32(pf.v, vf0, accO0);
        accO1 = MFMA32(pf.v, vf1, accO1);
        accL  = MFMA32(pf.v, onesb, accL);   // denominator rowsum
        __builtin_amdgcn_s_setprio(0);
      }
    }
  }
  // epilogue: lane-local divide (accL[r] = rowsum for this r's q-row)
  #pragma unroll
  for(int r=0;r<16;r++){
    int qs = (r&3) + ((r>>2)<<3) + (h<<2);
    float li = rcp_fast(accL[r]);
    size_t o = (size_t)(b*1024 + Qb + qs)*1024 + hd*64 + ql;
    Out[o]      = f2bf(accO0[r]*li);
    Out[o + 32] = f2bf(accO1[r]*li);
  }
#undef LDV
#undef STV
#undef KDMA
}

extern "C" void kernel_launch(void* const* d_in, const int* in_sizes, int n_in,
                              void* d_out, int out_size, void* d_ws, size_t ws_size,
                              hipStream_t stream) {
  const float* x      = (const float*)d_in[0];
  const float* cosT   = (const float*)d_in[1];
  const float* sinT   = (const float*)d_in[2];
  const float* w_qkv  = (const float*)d_in[3];
  const float* w_proj = (const float*)d_in[4];
  const float* qw     = (const float*)d_in[5];
  const float* kw     = (const float*)d_in[6];
  float* out = (float*)d_out;

  // ws layout (u16 units): xb dead after qkv GEMM -> attn aliases it.
  u16* xb     = (u16*)d_ws;                         //  8388608 elems
  u16* wqkvb  = xb     + (size_t) 8388608;          //  3145728
  u16* wprojb = wqkvb  + (size_t) 3145728;          //  1048576
  u16* qkv    = wprojb + (size_t) 1048576;          // 25165824
  u16* attn   = xb;                                 //  8388608 (alias)

  cvt3<<<3072, 256, 0, stream>>>(x, w_qkv, w_proj, xb);

  gemm_bt<2><<<1536, 256, 0, stream>>>(xb, wqkvb, qkv, 8192, 3072, 1024,
                                       cosT, sinT, qw, kw);
  fattn   <<<512, 512, 0, stream>>>(qkv, attn);
  gemm_bt<1><<<512, 256, 0, stream>>>(attn, wprojb, out, 8192, 1024, 1024,
                                      nullptr, nullptr, nullptr, nullptr);
}